// Round 1
// baseline (12069.588 us; speedup 1.0000x reference)
//
#include <hip/hip_runtime.h>
#include <stdint.h>

#define B_ 16
#define S_ 2048
#define H_ 512
#define M_ (B_ * S_)  // 32768 rows in all big GEMMs

// ---------------------------------------------------------------------------
// GEMM: Y[M,N] = X[M,K] @ W[N,K]^T + b1[N] (+ b2[N]), optional tanh epilogue.
// 128x128 tile, BK=16, 256 threads, 8x8 micro-tile per thread. fp32 VALU.
// (unchanged)
// ---------------------------------------------------------------------------
template <int ACT>
__global__ __launch_bounds__(256) void gemm_xwt(
    const float* __restrict__ X, const float* __restrict__ W,
    const float* __restrict__ b1, const float* __restrict__ b2,
    float* __restrict__ Y, int K, int ldy)
{
  __shared__ float As[16][132];
  __shared__ float Bs[16][132];
  const int tid = threadIdx.x;
  const int bm = blockIdx.x, bn = blockIdx.y;
  const int ty = tid >> 4, tx = tid & 15;      // 16x16 thread grid
  const int lr = tid >> 2, lk = (tid & 3) << 2; // staging: 64 rows x 4 k-quads
  const float* Xb = X + (size_t)(bm * 128) * K;
  const float* Wb = W + (size_t)(bn * 128) * K;

  float acc[8][8] = {};

  for (int k0 = 0; k0 < K; k0 += 16) {
    float4 xa0 = *(const float4*)(Xb + (size_t)lr * K + k0 + lk);
    float4 xa1 = *(const float4*)(Xb + (size_t)(lr + 64) * K + k0 + lk);
    float4 wa0 = *(const float4*)(Wb + (size_t)lr * K + k0 + lk);
    float4 wa1 = *(const float4*)(Wb + (size_t)(lr + 64) * K + k0 + lk);
    __syncthreads();
    As[lk + 0][lr] = xa0.x; As[lk + 1][lr] = xa0.y; As[lk + 2][lr] = xa0.z; As[lk + 3][lr] = xa0.w;
    As[lk + 0][lr + 64] = xa1.x; As[lk + 1][lr + 64] = xa1.y; As[lk + 2][lr + 64] = xa1.z; As[lk + 3][lr + 64] = xa1.w;
    Bs[lk + 0][lr] = wa0.x; Bs[lk + 1][lr] = wa0.y; Bs[lk + 2][lr] = wa0.z; Bs[lk + 3][lr] = wa0.w;
    Bs[lk + 0][lr + 64] = wa1.x; Bs[lk + 1][lr + 64] = wa1.y; Bs[lk + 2][lr + 64] = wa1.z; Bs[lk + 3][lr + 64] = wa1.w;
    __syncthreads();
#pragma unroll
    for (int kk = 0; kk < 16; ++kk) {
      float4 a0 = *(const float4*)&As[kk][ty * 8];
      float4 a1 = *(const float4*)&As[kk][ty * 8 + 4];
      float4 b0 = *(const float4*)&Bs[kk][tx * 8];
      float4 b1v = *(const float4*)&Bs[kk][tx * 8 + 4];
      float av[8] = {a0.x, a0.y, a0.z, a0.w, a1.x, a1.y, a1.z, a1.w};
      float bv[8] = {b0.x, b0.y, b0.z, b0.w, b1v.x, b1v.y, b1v.z, b1v.w};
#pragma unroll
      for (int i = 0; i < 8; ++i)
#pragma unroll
        for (int j = 0; j < 8; ++j) acc[i][j] += av[i] * bv[j];
    }
  }

  const int ncol0 = bn * 128 + tx * 8;
  float bias[8];
#pragma unroll
  for (int j = 0; j < 8; ++j) {
    float bb = b1[ncol0 + j];
    if (b2) bb += b2[ncol0 + j];
    bias[j] = bb;
  }
#pragma unroll
  for (int i = 0; i < 8; ++i) {
    size_t row = (size_t)bm * 128 + ty * 8 + i;
    float* yp = Y + row * (size_t)ldy + ncol0;
    float out[8];
#pragma unroll
    for (int j = 0; j < 8; ++j) {
      float v = acc[i][j] + bias[j];
      if (ACT) v = tanhf(v);
      out[j] = v;
    }
    *(float4*)(yp)     = make_float4(out[0], out[1], out[2], out[3]);
    *(float4*)(yp + 4) = make_float4(out[4], out[5], out[6], out[7]);
  }
}

// ---------------------------------------------------------------------------
// Attention fusion (unchanged).
// ---------------------------------------------------------------------------
__global__ __launch_bounds__(256) void fusion_kernel(
    const float* __restrict__ F,    // [M, 1536] = a|v|l
    const float* __restrict__ CTX,  // [M, 512]
    float* __restrict__ FU)         // [M, 512]
{
  const int row = blockIdx.x * 4 + (threadIdx.x >> 6);
  const int lane = threadIdx.x & 63;
  const float* a = F + (size_t)row * 1536;
  const float* v = a + 512;
  const float* l = a + 1024;
  const float* c = CTX + (size_t)row * 512;
  float sa = 0.f, sv = 0.f, sl = 0.f;
  for (int k = lane; k < 512; k += 64) {
    float cv = c[k];
    sa += a[k] * cv; sv += v[k] * cv; sl += l[k] * cv;
  }
#pragma unroll
  for (int off = 1; off < 64; off <<= 1) {
    sa += __shfl_xor(sa, off);
    sv += __shfl_xor(sv, off);
    sl += __shfl_xor(sl, off);
  }
  float m = fmaxf(sa, fmaxf(sv, sl));
  float ea = expf(sa - m), ev = expf(sv - m), el = expf(sl - m);
  float inv = 1.0f / (ea + ev + el);
  float wa = ea * inv, wv = ev * inv, wl = el * inv;
  float* fu = FU + (size_t)row * 512;
  for (int k = lane; k < 512; k += 64)
    fu[k] = wa * a[k] + wv * v[k] + wl * l[k];
}

// ---------------------------------------------------------------------------
// Persistent LSTM, v2: publish GATES (not h), redundant h/c per WG.
//
// Protocol per step t (per WG):
//   dot: sum = Whh[slice] . h(t-1)                 (h in LDS, double-buffered)
//   publish sum tagged t into ring[t&1][b][gcol]   (khalf==0 lanes, 128 words)
//   poll ALL 8 gate words this thread needs (one batched load round)
//   compute c(t), h(t) redundantly (2 units/thread, c in registers)
//   issue G(t+1) prefetch (consumed NEXT step -> retired before next poll's
//     vmcnt(0), so HBM latency never lands in the detect path)
//   ds_write h(t) to the other LDS buffer; ONE __syncthreads
//
// vs v1 this removes: one barrier, the 32-lane serialized nonlinearity+store
// tail, the second sequential poll loop, and the G load drain inside the spin.
// Tag-in-word (payload travels with flag) -> no fences. Ring depth 2 is
// lap-safe: publish(t) precedes poll(t), so WG skew in publish-steps <= 1,
// and tags (0..2047) are unique per step; stale tags from the previous graph
// iteration are 2046/2047 (or 0xAAAAAAAA poison) and can never match early
// wants, and slots are rewritten in order before their want comes around.
// 16 WGs/batch on one XCD (same %8 swizzle), 1 WG/CU guaranteed by register
// footprint (warr = 256 floats/thread in AGPRs).
// ---------------------------------------------------------------------------
__device__ __forceinline__ float sigf(float x) { return 1.f / (1.f + expf(-x)); }
__device__ __forceinline__ float lo32f(unsigned long long w) {
  return __builtin_bit_cast(float, (unsigned int)w);
}

__global__ __launch_bounds__(256, 1) void lstm_kernel(
    const float* __restrict__ G,    // [B*S, 2048] precomputed x@Wih.T + biases
    const float* __restrict__ Whh,  // [2048, 512]
    const float* __restrict__ h0,   // [B, 512]
    const float* __restrict__ c0,   // [B, 512]
    unsigned long long* __restrict__ ring,  // [2][B][2048] tagged gate words
    float* __restrict__ r_out,      // [B, S, 512]
    float* __restrict__ hT,         // [B, 512]
    float* __restrict__ cT)         // [B, 512]
{
  const int bi = blockIdx.x;
  const int b  = ((bi & 7) << 1) | ((bi >> 3) & 1);  // batch; 16 WGs/batch -> 1 XCD
  const int wg = bi >> 4;
  const int k0h = wg << 5;  // hidden-slice base (32 units) this WG produces
  const int tid = threadIdx.x;

  __shared__ float h_lds[2][512];   // double-buffered h -> one barrier/step

  // --- dot-phase mapping (unchanged from v1) ---
  const int col = tid >> 1;        // 0..127 local gate row
  const int khalf = tid & 1;       // k-half of the 512-dot
  const int kbase = khalf << 8;    // 0 or 256
  const int g = col >> 5, ul = col & 31;
  const int gcol = g * 512 + k0h + ul;  // global gate row 0..2047

  // Whh slice into registers (AGPR-backed), one-time
  float4 warr[64];
  const float* wsrc = Whh + (size_t)gcol * 512 + kbase;
#pragma unroll
  for (int j = 0; j < 64; ++j) warr[j] = *(const float4*)(wsrc + j * 4);

  // --- consumer-phase mapping: thread owns units u0, u0+1 ---
  const int u0 = tid << 1;
  const float* Gb = G + (size_t)b * S_ * 2048;
  const bool writer = ((tid >> 4) == wg);  // 16 threads own this WG's h slice

  // preamble: h(-1)=h0 into LDS buf0; c from c0; G(0) into registers
  h_lds[0][tid]       = h0[b * H_ + tid];
  h_lds[0][tid + 256] = h0[b * H_ + tid + 256];
  float c_a = c0[b * H_ + u0];
  float c_b = c0[b * H_ + u0 + 1];
  float2 gv_i = *(const float2*)(Gb + u0);
  float2 gv_f = *(const float2*)(Gb + 512 + u0);
  float2 gv_g = *(const float2*)(Gb + 1024 + u0);
  float2 gv_o = *(const float2*)(Gb + 1536 + u0);
  __syncthreads();

  int buf = 0;
  for (int t = 0; t < S_; ++t) {
    // ---- dot over h(t-1) ----
    const float* hb = &h_lds[buf][kbase];
    float4 s4 = make_float4(0.f, 0.f, 0.f, 0.f);
#pragma unroll
    for (int j = 0; j < 64; ++j) {
      float4 hv = *(const float4*)(hb + (j << 2));
      s4.x += warr[j].x * hv.x;
      s4.y += warr[j].y * hv.y;
      s4.z += warr[j].z * hv.z;
      s4.w += warr[j].w * hv.w;
    }
    float sum = (s4.x + s4.y) + (s4.z + s4.w);
    sum += __shfl_xor(sum, 1);

    // ---- publish raw gate sum (tag t in high word) ----
    unsigned long long* slot = ring + ((size_t)((t & 1) * B_ + b)) * 2048;
    if (khalf == 0) {
      unsigned long long pk =
          ((unsigned long long)(unsigned int)t << 32) |
          (unsigned long long)__builtin_bit_cast(unsigned int, sum);
      __hip_atomic_store(slot + gcol, pk, __ATOMIC_RELAXED,
                         __HIP_MEMORY_SCOPE_AGENT);
    }

    // ---- batched poll: all 8 words this thread needs, one round trip ----
    const unsigned long long* sp = slot + u0;
    const unsigned int want = (unsigned int)t;
    unsigned long long wi0, wi1, wf0, wf1, wg0, wg1, wo0, wo1;
    for (;;) {
      wi0 = __hip_atomic_load(sp + 0,    __ATOMIC_RELAXED, __HIP_MEMORY_SCOPE_AGENT);
      wi1 = __hip_atomic_load(sp + 1,    __ATOMIC_RELAXED, __HIP_MEMORY_SCOPE_AGENT);
      wf0 = __hip_atomic_load(sp + 512,  __ATOMIC_RELAXED, __HIP_MEMORY_SCOPE_AGENT);
      wf1 = __hip_atomic_load(sp + 513,  __ATOMIC_RELAXED, __HIP_MEMORY_SCOPE_AGENT);
      wg0 = __hip_atomic_load(sp + 1024, __ATOMIC_RELAXED, __HIP_MEMORY_SCOPE_AGENT);
      wg1 = __hip_atomic_load(sp + 1025, __ATOMIC_RELAXED, __HIP_MEMORY_SCOPE_AGENT);
      wo0 = __hip_atomic_load(sp + 1536, __ATOMIC_RELAXED, __HIP_MEMORY_SCOPE_AGENT);
      wo1 = __hip_atomic_load(sp + 1537, __ATOMIC_RELAXED, __HIP_MEMORY_SCOPE_AGENT);
      unsigned int bad =
          ((unsigned int)(wi0 >> 32) ^ want) | ((unsigned int)(wi1 >> 32) ^ want) |
          ((unsigned int)(wf0 >> 32) ^ want) | ((unsigned int)(wf1 >> 32) ^ want) |
          ((unsigned int)(wg0 >> 32) ^ want) | ((unsigned int)(wg1 >> 32) ^ want) |
          ((unsigned int)(wo0 >> 32) ^ want) | ((unsigned int)(wo1 >> 32) ^ want);
      if (bad == 0) break;
    }

    // consume current G regs, then issue NEXT step's G loads immediately
    // (they retire during h-compute + barrier + dot -> never stall a poll)
    float Gi0 = gv_i.x, Gi1 = gv_i.y, Gf0 = gv_f.x, Gf1 = gv_f.y;
    float Gg0 = gv_g.x, Gg1 = gv_g.y, Go0 = gv_o.x, Go1 = gv_o.y;
    if (t + 1 < S_) {
      const float* gn = Gb + (size_t)(t + 1) * 2048 + u0;
      gv_i = *(const float2*)(gn);
      gv_f = *(const float2*)(gn + 512);
      gv_g = *(const float2*)(gn + 1024);
      gv_o = *(const float2*)(gn + 1536);
    }

    // ---- redundant h/c update for units u0, u0+1 ----
    float i0 = lo32f(wi0) + Gi0, i1 = lo32f(wi1) + Gi1;
    float f0 = lo32f(wf0) + Gf0, f1 = lo32f(wf1) + Gf1;
    float g0 = lo32f(wg0) + Gg0, g1 = lo32f(wg1) + Gg1;
    float o0 = lo32f(wo0) + Go0, o1 = lo32f(wo1) + Go1;

    float cA = sigf(f0) * c_a + sigf(i0) * tanhf(g0);
    float cB = sigf(f1) * c_b + sigf(i1) * tanhf(g1);
    c_a = cA; c_b = cB;
    float hA = sigf(o0) * tanhf(cA);
    float hB = sigf(o1) * tanhf(cB);

    *(float2*)&h_lds[buf ^ 1][u0] = make_float2(hA, hB);
    if (writer) {
      *(float2*)(r_out + ((size_t)b * S_ + t) * H_ + u0) = make_float2(hA, hB);
      if (t == S_ - 1) {
        *(float2*)(hT + b * H_ + u0) = make_float2(hA, hB);
        *(float2*)(cT + b * H_ + u0) = make_float2(cA, cB);
      }
    }
    __syncthreads();   // the ONLY barrier per step
    buf ^= 1;
  }
}

// ---------------------------------------------------------------------------
// ws layout (bytes):
//   [0, 256MB)        : F [32768,1536] fp32 (a|v|l), later reused as G [32768,2048]
//   [256MB, 320MB)    : CTX [32768,512]
//   [320MB, 384MB)    : FU  [32768,512]
//   [384MB, +512KB)   : tagged gate ring [2][16][2048] x u64
// Total < 385 MB (same envelope as v1).
// ---------------------------------------------------------------------------
extern "C" void kernel_launch(void* const* d_in, const int* in_sizes, int n_in,
                              void* d_out, int out_size, void* d_ws, size_t ws_size,
                              hipStream_t stream)
{
  const float* a_in = (const float*)d_in[0];
  const float* v_in = (const float*)d_in[1];
  const float* l_in = (const float*)d_in[2];
  const float* h0   = (const float*)d_in[3];
  const float* c0   = (const float*)d_in[4];
  const float* Wa = (const float*)d_in[5];   const float* ba = (const float*)d_in[6];
  const float* Wv = (const float*)d_in[7];   const float* bv = (const float*)d_in[8];
  const float* Wl = (const float*)d_in[9];   const float* bl = (const float*)d_in[10];
  const float* Wc = (const float*)d_in[11];  const float* bc = (const float*)d_in[12];
  const float* Wih = (const float*)d_in[13]; const float* Whh = (const float*)d_in[14];
  const float* bih = (const float*)d_in[15]; const float* bhh = (const float*)d_in[16];

  char* ws = (char*)d_ws;
  float* Fbuf = (float*)ws;                       // also Gbuf after fusion
  float* Gbuf = (float*)ws;
  float* CTX  = (float*)(ws + 268435456ull);
  float* FU   = (float*)(ws + 335544320ull);
  unsigned long long* ringp = (unsigned long long*)(ws + 402653184ull);

  dim3 blk(256);
  // projections into F (ld 1536): a|v|l
  gemm_xwt<0><<<dim3(256, 4), blk, 0, stream>>>(a_in, Wa, ba, nullptr, Fbuf + 0,    512,  1536);
  gemm_xwt<0><<<dim3(256, 4), blk, 0, stream>>>(v_in, Wv, bv, nullptr, Fbuf + 512,  768,  1536);
  gemm_xwt<0><<<dim3(256, 4), blk, 0, stream>>>(l_in, Wl, bl, nullptr, Fbuf + 1024, 1024, 1536);
  // context = tanh(F @ Wc^T + bc)
  gemm_xwt<1><<<dim3(256, 4), blk, 0, stream>>>(Fbuf, Wc, bc, nullptr, CTX, 1536, 512);
  // softmax-weighted fusion
  fusion_kernel<<<dim3(8192), blk, 0, stream>>>(Fbuf, CTX, FU);
  // G = FU @ Wih^T + bih + bhh   (overwrites F region — F is dead)
  gemm_xwt<0><<<dim3(256, 16), blk, 0, stream>>>(FU, Wih, bih, bhh, Gbuf, 512, 2048);
  // persistent sequential LSTM (gate ring, tag-in-word; no memset needed)
  float* out = (float*)d_out;
  lstm_kernel<<<dim3(256), blk, 0, stream>>>(Gbuf, Whh, h0, c0, ringp,
                                             out, out + 16777216ull,
                                             out + 16777216ull + 8192ull);
}

// Round 2
// 10495.627 us; speedup vs baseline: 1.1500x; 1.1500x over previous
//
#include <hip/hip_runtime.h>
#include <stdint.h>

#define B_ 16
#define S_ 2048
#define H_ 512
#define M_ (B_ * S_)  // 32768 rows in all big GEMMs

// ---------------------------------------------------------------------------
// GEMM: Y[M,N] = X[M,K] @ W[N,K]^T + b1[N] (+ b2[N]), optional tanh epilogue.
// 128x128 tile, BK=16, 256 threads, 8x8 micro-tile per thread. fp32 VALU.
// (unchanged)
// ---------------------------------------------------------------------------
template <int ACT>
__global__ __launch_bounds__(256) void gemm_xwt(
    const float* __restrict__ X, const float* __restrict__ W,
    const float* __restrict__ b1, const float* __restrict__ b2,
    float* __restrict__ Y, int K, int ldy)
{
  __shared__ float As[16][132];
  __shared__ float Bs[16][132];
  const int tid = threadIdx.x;
  const int bm = blockIdx.x, bn = blockIdx.y;
  const int ty = tid >> 4, tx = tid & 15;      // 16x16 thread grid
  const int lr = tid >> 2, lk = (tid & 3) << 2; // staging: 64 rows x 4 k-quads
  const float* Xb = X + (size_t)(bm * 128) * K;
  const float* Wb = W + (size_t)(bn * 128) * K;

  float acc[8][8] = {};

  for (int k0 = 0; k0 < K; k0 += 16) {
    float4 xa0 = *(const float4*)(Xb + (size_t)lr * K + k0 + lk);
    float4 xa1 = *(const float4*)(Xb + (size_t)(lr + 64) * K + k0 + lk);
    float4 wa0 = *(const float4*)(Wb + (size_t)lr * K + k0 + lk);
    float4 wa1 = *(const float4*)(Wb + (size_t)(lr + 64) * K + k0 + lk);
    __syncthreads();
    As[lk + 0][lr] = xa0.x; As[lk + 1][lr] = xa0.y; As[lk + 2][lr] = xa0.z; As[lk + 3][lr] = xa0.w;
    As[lk + 0][lr + 64] = xa1.x; As[lk + 1][lr + 64] = xa1.y; As[lk + 2][lr + 64] = xa1.z; As[lk + 3][lr + 64] = xa1.w;
    Bs[lk + 0][lr] = wa0.x; Bs[lk + 1][lr] = wa0.y; Bs[lk + 2][lr] = wa0.z; Bs[lk + 3][lr] = wa0.w;
    Bs[lk + 0][lr + 64] = wa1.x; Bs[lk + 1][lr + 64] = wa1.y; Bs[lk + 2][lr + 64] = wa1.z; Bs[lk + 3][lr + 64] = wa1.w;
    __syncthreads();
#pragma unroll
    for (int kk = 0; kk < 16; ++kk) {
      float4 a0 = *(const float4*)&As[kk][ty * 8];
      float4 a1 = *(const float4*)&As[kk][ty * 8 + 4];
      float4 b0 = *(const float4*)&Bs[kk][tx * 8];
      float4 b1v = *(const float4*)&Bs[kk][tx * 8 + 4];
      float av[8] = {a0.x, a0.y, a0.z, a0.w, a1.x, a1.y, a1.z, a1.w};
      float bv[8] = {b0.x, b0.y, b0.z, b0.w, b1v.x, b1v.y, b1v.z, b1v.w};
#pragma unroll
      for (int i = 0; i < 8; ++i)
#pragma unroll
        for (int j = 0; j < 8; ++j) acc[i][j] += av[i] * bv[j];
    }
  }

  const int ncol0 = bn * 128 + tx * 8;
  float bias[8];
#pragma unroll
  for (int j = 0; j < 8; ++j) {
    float bb = b1[ncol0 + j];
    if (b2) bb += b2[ncol0 + j];
    bias[j] = bb;
  }
#pragma unroll
  for (int i = 0; i < 8; ++i) {
    size_t row = (size_t)bm * 128 + ty * 8 + i;
    float* yp = Y + row * (size_t)ldy + ncol0;
    float out[8];
#pragma unroll
    for (int j = 0; j < 8; ++j) {
      float v = acc[i][j] + bias[j];
      if (ACT) v = tanhf(v);
      out[j] = v;
    }
    *(float4*)(yp)     = make_float4(out[0], out[1], out[2], out[3]);
    *(float4*)(yp + 4) = make_float4(out[4], out[5], out[6], out[7]);
  }
}

// ---------------------------------------------------------------------------
// Attention fusion (unchanged).
// ---------------------------------------------------------------------------
__global__ __launch_bounds__(256) void fusion_kernel(
    const float* __restrict__ F,    // [M, 1536] = a|v|l
    const float* __restrict__ CTX,  // [M, 512]
    float* __restrict__ FU)         // [M, 512]
{
  const int row = blockIdx.x * 4 + (threadIdx.x >> 6);
  const int lane = threadIdx.x & 63;
  const float* a = F + (size_t)row * 1536;
  const float* v = a + 512;
  const float* l = a + 1024;
  const float* c = CTX + (size_t)row * 512;
  float sa = 0.f, sv = 0.f, sl = 0.f;
  for (int k = lane; k < 512; k += 64) {
    float cv = c[k];
    sa += a[k] * cv; sv += v[k] * cv; sl += l[k] * cv;
  }
#pragma unroll
  for (int off = 1; off < 64; off <<= 1) {
    sa += __shfl_xor(sa, off);
    sv += __shfl_xor(sv, off);
    sl += __shfl_xor(sl, off);
  }
  float m = fmaxf(sa, fmaxf(sv, sl));
  float ea = expf(sa - m), ev = expf(sv - m), el = expf(sl - m);
  float inv = 1.0f / (ea + ev + el);
  float wa = ea * inv, wv = ev * inv, wl = el * inv;
  float* fu = FU + (size_t)row * 512;
  for (int k = lane; k < 512; k += 64)
    fu[k] = wa * a[k] + wv * v[k] + wl * l[k];
}

// ---------------------------------------------------------------------------
// Persistent LSTM v3 = v1 dataflow + low-contention sync.
//
// Post-mortem of v2: agent-scope atomics are serviced at the IF$/coherence
// point (WRITE_SIZE tripled = ring writes reach L2->EA), so every poll
// iteration is a ~700cy fabric round trip AND 256 WGs spinning on 4KB each
// queue up at the fabric. v3 keeps v1's bitwise-identical math (publish h,
// 32-lane tail) and restructures only the detect path:
//   - producer lane 0 stores ONE tagged sentinel word after its h-words
//   - consumer spin = wave0 lanes 0..15 polling 16 packed sentinels
//     (128B/iteration instead of 4KB/iteration -> ~30x less spin traffic)
//   - after detect + barrier, all 256 threads do a ONE-SHOT read of their
//     2 tagged h-words; tag-verify loop covers sentinel/payload completion
//     reordering (no fences anywhere)
//   - G(t+1) prefetch issues after the payload read -> HBM latency drains
//     under barrier+dot, never under a spin waitcnt
// Ring depth 4, tags unique per step, 0xAA poison never matches, skew <= 1.
// Grid = 256 WGs = 1/CU (co-resident by construction, same as v1/v2).
// ---------------------------------------------------------------------------
__device__ __forceinline__ float sigf(float x) { return 1.f / (1.f + expf(-x)); }
__device__ __forceinline__ float lo32f(unsigned long long w) {
  return __builtin_bit_cast(float, (unsigned int)w);
}

__global__ __launch_bounds__(256, 1) void lstm_kernel(
    const float* __restrict__ G,    // [B*S, 2048] precomputed x@Wih.T + biases
    const float* __restrict__ Whh,  // [2048, 512]
    const float* __restrict__ h0,   // [B, 512]
    const float* __restrict__ c0,   // [B, 512]
    unsigned long long* __restrict__ ring,  // [4][B][512] tagged h words
    unsigned long long* __restrict__ sent,  // [4][B][16]  tagged sentinels
    float* __restrict__ r_out,      // [B, S, 512]
    float* __restrict__ hT,         // [B, 512]
    float* __restrict__ cT)         // [B, 512]
{
  const int bi = blockIdx.x;
  const int b  = ((bi & 7) << 1) | ((bi >> 3) & 1);  // 16 WGs/batch -> 1 XCD
  const int wg = bi >> 4;
  const int k0h = wg << 5;  // hidden-slice base (32 units)
  const int tid = threadIdx.x;

  __shared__ float h_lds[2][512];   // double-buffered h
  __shared__ float gates_lds[128];
  __shared__ float c_lds[32];

  // dot-phase mapping (identical to v1)
  const int col = tid >> 1;       // 0..127 local gate row
  const int khalf = tid & 1;      // k-half of the 512-dot
  const int kbase = khalf << 8;   // 0 or 256
  const int g = col >> 5, ul = col & 31;
  const int gcol = g * 512 + k0h + ul;  // row in Whh == column in G

  // Whh slice into registers (AGPR-backed), one-time
  float4 warr[64];
  const float* wsrc = Whh + (size_t)gcol * 512 + kbase;
#pragma unroll
  for (int j = 0; j < 64; ++j) warr[j] = *(const float4*)(wsrc + j * 4);

  const float* gbase = G + (size_t)b * S_ * 2048;

  if (tid < 32) c_lds[tid] = c0[b * H_ + k0h + tid];
  h_lds[0][tid]       = h0[b * H_ + tid];
  h_lds[0][tid + 256] = h0[b * H_ + tid + 256];
  float gval = (khalf == 0) ? gbase[gcol] : 0.f;   // G(0), prefetched
  __syncthreads();

  int buf = 0;
  for (int t = 0; t < S_; ++t) {
    // ---- dot over h(t-1) (bitwise-identical to v1) ----
    const float* hb = &h_lds[buf][kbase];
    float4 s4 = make_float4(0.f, 0.f, 0.f, 0.f);
#pragma unroll
    for (int j = 0; j < 64; ++j) {
      float4 hv = *(const float4*)(hb + (j << 2));
      s4.x += warr[j].x * hv.x;
      s4.y += warr[j].y * hv.y;
      s4.z += warr[j].z * hv.z;
      s4.w += warr[j].w * hv.w;
    }
    float sum = (s4.x + s4.y) + (s4.z + s4.w);
    sum += __shfl_xor(sum, 1);
    if (khalf == 0) gates_lds[col] = sum + gval;
    __syncthreads();   // A: gates ready

    unsigned long long* slot = ring + ((size_t)(t & 3) * B_ + b) * H_;

    // ---- producer tail: 32 lanes, nonlinearity + tagged publish ----
    if (tid < 32) {
      const int u = tid;
      float ip = gates_lds[u], fp = gates_lds[32 + u];
      float gp = gates_lds[64 + u], op = gates_lds[96 + u];
      float ig = sigf(ip), fg = sigf(fp);
      float gg = tanhf(gp), og = sigf(op);
      float cn = fg * c_lds[u] + ig * gg;
      c_lds[u] = cn;
      float hn = og * tanhf(cn);
      unsigned long long pk =
          ((unsigned long long)(unsigned int)t << 32) |
          (unsigned long long)__builtin_bit_cast(unsigned int, hn);
      __hip_atomic_store(slot + k0h + u, pk, __ATOMIC_RELAXED,
                         __HIP_MEMORY_SCOPE_AGENT);
      if (u == 0) {
        // sentinel AFTER the wave's 32 h-stores in program order (hint only;
        // payload tag-verify covers completion reordering)
        __hip_atomic_store(sent + ((size_t)(t & 3) * B_ + b) * 16 + wg,
                           (unsigned long long)(unsigned int)t << 32,
                           __ATOMIC_RELAXED, __HIP_MEMORY_SCOPE_AGENT);
      }
      r_out[((size_t)b * S_ + t) * H_ + k0h + u] = hn;
      if (t == S_ - 1) {
        hT[b * H_ + k0h + u] = hn;
        cT[b * H_ + k0h + u] = cn;
      }
    }

    if (t + 1 < S_) {
      // ---- cheap detect: wave0 lanes 0..15 spin on 16 packed sentinels ----
      if (tid < 16) {
        const unsigned long long* sp =
            sent + ((size_t)(t & 3) * B_ + b) * 16 + tid;
        unsigned int got;
        do {
          got = (unsigned int)(__hip_atomic_load(sp, __ATOMIC_RELAXED,
                                                 __HIP_MEMORY_SCOPE_AGENT) >> 32);
        } while (got != (unsigned int)t);
      }
      __syncthreads();   // B: all producers have issued their publishes

      // ---- one-shot verified payload read (2 tagged words / thread) ----
      const unsigned int want = (unsigned int)t;
      unsigned long long v0 = __hip_atomic_load(slot + tid, __ATOMIC_RELAXED,
                                                __HIP_MEMORY_SCOPE_AGENT);
      unsigned long long v1 = __hip_atomic_load(slot + tid + 256, __ATOMIC_RELAXED,
                                                __HIP_MEMORY_SCOPE_AGENT);
      while ((((unsigned int)(v0 >> 32)) ^ want) |
             (((unsigned int)(v1 >> 32)) ^ want)) {
        v0 = __hip_atomic_load(slot + tid, __ATOMIC_RELAXED,
                               __HIP_MEMORY_SCOPE_AGENT);
        v1 = __hip_atomic_load(slot + tid + 256, __ATOMIC_RELAXED,
                               __HIP_MEMORY_SCOPE_AGENT);
      }
      h_lds[buf ^ 1][tid]       = lo32f(v0);
      h_lds[buf ^ 1][tid + 256] = lo32f(v1);

      // ---- G(t+1) prefetch: issued last, drains under barrier + next dot ----
      if (khalf == 0) gval = gbase[(size_t)(t + 1) * 2048 + gcol];
      __syncthreads();   // C: h(t) staged for next dot
      buf ^= 1;
    }
  }
}

// ---------------------------------------------------------------------------
// ws layout (bytes):
//   [0, 256MB)            : F [32768,1536] fp32 (a|v|l), reused as G [32768,2048]
//   [256MB, 320MB)        : CTX [32768,512]
//   [320MB, 384MB)        : FU  [32768,512]
//   [384MB, +256KB)       : tagged h ring [4][16][512] x u64
//   [384MB+256KB, +8KB)   : tagged sentinels [4][16][16] x u64
// Total < 385 MB (same envelope as v1/v2).
// ---------------------------------------------------------------------------
extern "C" void kernel_launch(void* const* d_in, const int* in_sizes, int n_in,
                              void* d_out, int out_size, void* d_ws, size_t ws_size,
                              hipStream_t stream)
{
  const float* a_in = (const float*)d_in[0];
  const float* v_in = (const float*)d_in[1];
  const float* l_in = (const float*)d_in[2];
  const float* h0   = (const float*)d_in[3];
  const float* c0   = (const float*)d_in[4];
  const float* Wa = (const float*)d_in[5];   const float* ba = (const float*)d_in[6];
  const float* Wv = (const float*)d_in[7];   const float* bv = (const float*)d_in[8];
  const float* Wl = (const float*)d_in[9];   const float* bl = (const float*)d_in[10];
  const float* Wc = (const float*)d_in[11];  const float* bc = (const float*)d_in[12];
  const float* Wih = (const float*)d_in[13]; const float* Whh = (const float*)d_in[14];
  const float* bih = (const float*)d_in[15]; const float* bhh = (const float*)d_in[16];

  char* ws = (char*)d_ws;
  float* Fbuf = (float*)ws;                       // also Gbuf after fusion
  float* Gbuf = (float*)ws;
  float* CTX  = (float*)(ws + 268435456ull);
  float* FU   = (float*)(ws + 335544320ull);
  unsigned long long* ringp = (unsigned long long*)(ws + 402653184ull);
  unsigned long long* sentp = (unsigned long long*)(ws + 402653184ull + 262144ull);

  dim3 blk(256);
  // projections into F (ld 1536): a|v|l
  gemm_xwt<0><<<dim3(256, 4), blk, 0, stream>>>(a_in, Wa, ba, nullptr, Fbuf + 0,    512,  1536);
  gemm_xwt<0><<<dim3(256, 4), blk, 0, stream>>>(v_in, Wv, bv, nullptr, Fbuf + 512,  768,  1536);
  gemm_xwt<0><<<dim3(256, 4), blk, 0, stream>>>(l_in, Wl, bl, nullptr, Fbuf + 1024, 1024, 1536);
  // context = tanh(F @ Wc^T + bc)
  gemm_xwt<1><<<dim3(256, 4), blk, 0, stream>>>(Fbuf, Wc, bc, nullptr, CTX, 1536, 512);
  // softmax-weighted fusion
  fusion_kernel<<<dim3(8192), blk, 0, stream>>>(Fbuf, CTX, FU);
  // G = FU @ Wih^T + bih + bhh   (overwrites F region — F is dead)
  gemm_xwt<0><<<dim3(256, 16), blk, 0, stream>>>(FU, Wih, bih, bhh, Gbuf, 512, 2048);
  // persistent sequential LSTM (sentinel-accelerated tag sync)
  float* out = (float*)d_out;
  lstm_kernel<<<dim3(256), blk, 0, stream>>>(Gbuf, Whh, h0, c0, ringp, sentp,
                                             out, out + 16777216ull,
                                             out + 16777216ull + 8192ull);
}